// Round 7
// baseline (1633.943 us; speedup 1.0000x reference)
//
#include <hip/hip_runtime.h>
#include <hip/hip_bf16.h>

// Problem constants
constexpr int kB = 512, kT = 128, kF = 256, kH = 384, kK = 10, kLab = 25;
constexpr int kGates = 1542;        // 4H + 2L
constexpr int kNsw = 1552;          // 1536 swizzled gate cols + 6 logit + 10 pad (97 tiles)
constexpr int kWstride = 392;       // 384 K + 8 pad
constexpr int kSstride = 194;       // scratch [16 row][192 col + 2 pad] (even -> b64-able)

typedef short bf16x8 __attribute__((ext_vector_type(8)));
typedef float f32x4 __attribute__((ext_vector_type(4)));

__device__ __forceinline__ float sigm(float x) { return 1.f / (1.f + __expf(-x)); }

__device__ __forceinline__ unsigned short bf16bits(float x) {
  __hip_bfloat16 h = __float2bfloat16(x);
  return __builtin_bit_cast(unsigned short, h);
}

// swizzled col sc in [0,1536) -> original gate-space column
__device__ __forceinline__ int swcol_orig(int sc) {
  int ns = sc / 192, lc = sc % 192, w = lc / 48, wc = lc % 48;
  int g = wc / 12, jj = ns * 48 + w * 12 + wc % 12;
  int l = jj >> 7, ch = jj & 127;
  return 6 + (g * 3 + l) * 128 + ch;
}

// ---------------------------------------------------------------------------
// Prologue: build all swizzled bf16 weights + bias + zero h0 + zero sync cnt.
// ---------------------------------------------------------------------------
__global__ void prep_kernel(const float* __restrict__ kernel_w,
                            const float* __restrict__ kernel_b,
                            const float* __restrict__ rec_w,
                            const float* __restrict__ rec_b,
                            const float* __restrict__ conv_w,
                            __hip_bfloat16* __restrict__ Wr_lin,
                            __hip_bfloat16* __restrict__ Wlog,
                            __hip_bfloat16* __restrict__ Wx_sw,
                            __hip_bfloat16* __restrict__ W2sw,
                            float* __restrict__ bias,
                            __hip_bfloat16* __restrict__ Hh,
                            int* __restrict__ Cnt) {
  const long ntot = 1474560;  // W2sw size is the max job
  const long stride = (long)gridDim.x * blockDim.x;
  for (long i = (long)blockIdx.x * blockDim.x + threadIdx.x; i < ntot; i += stride) {
    // ---- W2sw: [c<120][n<384][32]
    {
      int j = (int)(i & 31);
      long r = i >> 5;
      int n = (int)(r % 384);
      int c = (int)(r / 384);
      int kk = c * 32 + j;
      int kc = kk / 384, h = kk % 384;
      W2sw[i] = __float2bfloat16(conv_w[((long)n * 384 + h) * 10 + kc]);
    }
    // ---- Wr_lin: 1536*384
    if (i < 589824) {
      int sc = (int)(i / 384), k = (int)(i % 384);
      Wr_lin[i] = __float2bfloat16(rec_w[(long)k * kGates + swcol_orig(sc)]);
    }
    // ---- Wx_sw: 8*1552*32 = 397312
    if (i < 397312) {
      int j = (int)(i & 31);
      long r = i >> 5;
      int n = (int)(r % kNsw);
      int c = (int)(r / kNsw);
      int k = c * 32 + j;
      int col = (n < 1536) ? swcol_orig(n) : ((n < 1542) ? (n - 1536) : -1);
      Wx_sw[i] = (col >= 0) ? __float2bfloat16(kernel_w[(long)k * kGates + col])
                            : __float2bfloat16(0.f);
    }
    // ---- Wlog: 12*16*32 = 6144
    if (i < 6144) {
      int j = (int)(i & 31);
      long r = i >> 5;
      int n = (int)(r % 16);
      int c = (int)(r / 16);
      int k = c * 32 + j;
      Wlog[i] = (n < 6) ? __float2bfloat16(rec_w[(long)k * kGates + n])
                        : __float2bfloat16(0.f);
    }
    // ---- bias
    if (i < kGates) {
      float b0 = kernel_b[i] + rec_b[i];
      bias[i] = b0;
      bias[kGates + i] = b0 + kernel_w[(long)kF * kGates + i] + rec_w[(long)kH * kGates + i];
    }
    // ---- zero h_{-1}
    if (i < (long)kB * kH) Hh[i] = __float2bfloat16(0.f);
    // ---- zero sync counters (ws is poisoned 0xAA before every launch)
    if (i < 1024) Cnt[i] = 0;
  }
}

// ---------------------------------------------------------------------------
// XW precompute: XW[t*512+b][1552] bf16 = X @ kernel_w (swizzled cols).
// ---------------------------------------------------------------------------
__global__ __launch_bounds__(256) void xw_kernel(const float* __restrict__ X,
                                                 const __hip_bfloat16* __restrict__ Wx_sw,
                                                 __hip_bfloat16* __restrict__ XW) {
  const int tid = threadIdx.x;
  const int lane = tid & 63, wave = tid >> 6;
  const int r16 = lane & 15, quad = lane >> 4;
  const int m0 = blockIdx.x * 64 + wave * 16;
  const int m = m0 + r16;
  const int t = m >> 9, b = m & 511;
  const float* xrow = X + ((size_t)b * kT + t) * kF;

  bf16x8 a[8];
#pragma unroll
  for (int c = 0; c < 8; ++c) {
    float4 p0 = *(const float4*)(xrow + c * 32 + quad * 8);
    float4 p1 = *(const float4*)(xrow + c * 32 + quad * 8 + 4);
    union { bf16x8 v; __hip_bfloat16 h[8]; } u;
    u.h[0] = __float2bfloat16(p0.x); u.h[1] = __float2bfloat16(p0.y);
    u.h[2] = __float2bfloat16(p0.z); u.h[3] = __float2bfloat16(p0.w);
    u.h[4] = __float2bfloat16(p1.x); u.h[5] = __float2bfloat16(p1.y);
    u.h[6] = __float2bfloat16(p1.z); u.h[7] = __float2bfloat16(p1.w);
    a[c] = u.v;
  }
  for (int tile = 0; tile < 97; ++tile) {
    f32x4 acc = (f32x4){0.f, 0.f, 0.f, 0.f};
#pragma unroll
    for (int c = 0; c < 8; ++c) {
      bf16x8 bf = *(const bf16x8*)(Wx_sw + ((size_t)c * kNsw + tile * 16 + r16) * 32 + quad * 8);
      acc = __builtin_amdgcn_mfma_f32_16x16x32_bf16(a[c], bf, acc, 0, 0, 0);
    }
#pragma unroll
    for (int r = 0; r < 4; ++r)
      XW[(size_t)(m0 + quad * 4 + r) * kNsw + tile * 16 + r16] = __float2bfloat16(acc[r]);
  }
}

// ---------------------------------------------------------------------------
// Persistent scan (R3-proven structure). 256 blocks (mt x ns), 256 threads.
// Sync: per-mt monotonic counter (fetch_add) at agent scope, tid0 poll +
// barrier; h exchanged via agent-scope relaxed atomics on canonical Hh.
// ONLY change vs R3: gate scratch transposed to [16 row][194 col] (scalar
// stores, 2-way banks) -- R3's [col][16] f32x4 stores were 8-way conflicted
// (SQ_LDS_BANK_CONFLICT 3.4e7). Lg stride 8->6 keeps LDS at 163840 B.
// LDS: W 192x392 bf16 (150528) | scratch 16x194 f32 (12416) | Lg 16x6 (384)
//      | fmS 16x4 (256) | imS 16x4 (256)  == 163840 B exactly.
// ---------------------------------------------------------------------------
__global__ __launch_bounds__(256, 1) void step_all(
    const __hip_bfloat16* __restrict__ Wr_lin, const __hip_bfloat16* __restrict__ Wlog,
    const float* __restrict__ bias, const __hip_bfloat16* __restrict__ XW,
    __hip_bfloat16* __restrict__ Hh, float* __restrict__ Dhist,
    int* __restrict__ Cnt) {
  extern __shared__ char smem[];
  __hip_bfloat16* Wl = (__hip_bfloat16*)smem;            // [192][392]
  float* scratch = (float*)(smem + 150528);              // [16 row][194]
  float* Lg = (float*)(smem + 162944);                   // [16][6]
  float* fmS = (float*)(smem + 163328);                  // [16][4]
  float* imS = (float*)(smem + 163584);                  // [16][4]

  const int bx = blockIdx.x;
  const int mt = bx >> 3, ns = bx & 7;
  const int tid = threadIdx.x;
  const int lane = tid & 63, wave = tid >> 6;
  const int r16 = lane & 15, quad = lane >> 4;
  const int brow = mt * 16 + r16;
  int* cnt = Cnt + mt * 32;   // 128B-padded per-mt counter

  // one-time: stage W slice (contiguous 192*384 bf16) into padded LDS
  {
    const __hip_bfloat16* src = Wr_lin + (size_t)ns * 192 * 384;
    for (int i = tid; i < 192 * 384 / 8; i += 256) {
      int lc = (i * 8) / 384, k = (i * 8) % 384;
      *(bf16x8*)(Wl + lc * kWstride + k) = *(const bf16x8*)(src + i * 8);
    }
  }
  __syncthreads();

  float creg[4] = {0.f, 0.f, 0.f, 0.f};

  for (int step = 0; step < kT; ++step) {
    const float* bt = bias + (step > 0 ? kGates : 0);

    // ---- XW prefetch (normal cached loads; independent of h) ----
    const __hip_bfloat16* XWrow = XW + (size_t)(step * kB + mt * 16) * kNsw;
    float xwv[3][4];
#pragma unroll
    for (int t3 = 0; t3 < 3; ++t3) {
      int col = ns * 192 + wave * 48 + t3 * 16 + r16;
#pragma unroll
      for (int r = 0; r < 4; ++r)
        xwv[t3][r] = __bfloat162float(XWrow[(size_t)(quad * 4 + r) * kNsw + col]);
    }
    float xlv[4] = {0.f, 0.f, 0.f, 0.f};
    if (wave == 0) {
#pragma unroll
      for (int r = 0; r < 4; ++r)
        xlv[r] = __bfloat162float(XWrow[(size_t)(quad * 4 + r) * kNsw + 1536 + r16]);
    }

    // ---- wait for all 8 ns-blocks of this mt to have published step's h ----
    if (step > 0) {
      if (tid == 0) {
        const int target = 8 * step;
        while (__hip_atomic_load(cnt, __ATOMIC_RELAXED, __HIP_MEMORY_SCOPE_AGENT) < target) {
        }
      }
      __syncthreads();
    }

    // ---- h fragment loads (agent-scope -> L3-coherent) ----
    bf16x8 a[12];
    {
      unsigned long long* Hq =
          (unsigned long long*)(Hh + ((size_t)step * kB + brow) * kH);
#pragma unroll
      for (int c = 0; c < 12; ++c) {
        union { unsigned long long q[2]; bf16x8 v; } u;
        u.q[0] = __hip_atomic_load(&Hq[c * 8 + quad * 2], __ATOMIC_RELAXED,
                                   __HIP_MEMORY_SCOPE_AGENT);
        u.q[1] = __hip_atomic_load(&Hq[c * 8 + quad * 2 + 1], __ATOMIC_RELAXED,
                                   __HIP_MEMORY_SCOPE_AGENT);
        a[c] = u.v;
      }
    }

    f32x4 acc[3];
#pragma unroll
    for (int t3 = 0; t3 < 3; ++t3) {
#pragma unroll
      for (int r = 0; r < 4; ++r) acc[t3][r] = xwv[t3][r];
    }
    f32x4 accL = (f32x4){xlv[0], xlv[1], xlv[2], xlv[3]};

#pragma unroll
    for (int c = 0; c < 12; ++c) {
#pragma unroll
      for (int t3 = 0; t3 < 3; ++t3) {
        bf16x8 bf = *(const bf16x8*)(Wl + (wave * 48 + t3 * 16 + r16) * kWstride + c * 32 + quad * 8);
        acc[t3] = __builtin_amdgcn_mfma_f32_16x16x32_bf16(a[c], bf, acc[t3], 0, 0, 0);
      }
      if (wave == 0) {
        bf16x8 bfl = *(const bf16x8*)(Wlog + ((size_t)c * 16 + r16) * 32 + quad * 8);
        accL = __builtin_amdgcn_mfma_f32_16x16x32_bf16(a[c], bfl, accL, 0, 0, 0);
      }
    }

    if (wave == 0 && r16 < 6) {
#pragma unroll
      for (int r = 0; r < 4; ++r) Lg[(quad * 4 + r) * 6 + r16] = accL[r] + bt[r16];
    }
#pragma unroll
    for (int t3 = 0; t3 < 3; ++t3) {
      int colb = wave * 48 + t3 * 16 + r16;
#pragma unroll
      for (int r = 0; r < 4; ++r) scratch[(quad * 4 + r) * kSstride + colb] = acc[t3][r];
    }
    __syncthreads();

    if (tid < 16) {
      float z0 = Lg[tid * 6 + 0], z1 = Lg[tid * 6 + 1], z2 = Lg[tid * 6 + 2];
      float m = fmaxf(z0, fmaxf(z1, z2));
      float e0 = __expf(z0 - m), e1 = __expf(z1 - m), e2 = __expf(z2 - m);
      float inv = 1.f / (e0 + e1 + e2);
      float fm0 = e0 * inv, fm1 = (e0 + e1) * inv, fm2 = 1.f;
      float z3 = Lg[tid * 6 + 3], z4 = Lg[tid * 6 + 4], z5 = Lg[tid * 6 + 5];
      float m2 = fmaxf(z3, fmaxf(z4, z5));
      float e3 = __expf(z3 - m2), e4 = __expf(z4 - m2), e5 = __expf(z5 - m2);
      float inv2 = 1.f / (e3 + e4 + e5);
      fmS[tid * 4 + 0] = fm0; fmS[tid * 4 + 1] = fm1; fmS[tid * 4 + 2] = fm2;
      imS[tid * 4 + 0] = 1.f;
      imS[tid * 4 + 1] = (e4 + e5) * inv2;
      imS[tid * 4 + 2] = e5 * inv2;
      if (ns == 0)
        Dhist[(size_t)step * kB + mt * 16 + tid] = 1.f - (fm0 + fm1 + fm2) * (1.f / 3.f);
    }
    __syncthreads();

    // ---- cell update + packed agent-scope h publish ----
    unsigned int* HoutU = (unsigned int*)(Hh + (size_t)(step + 1) * kB * kH);
#pragma unroll
    for (int it = 0; it < 2; ++it) {
      int p = tid + it * 256;
      if (p < 384) {
        int row = p & 15, cp = p >> 4;
        float hv[2];
#pragma unroll
        for (int e = 0; e < 2; ++e) {
          int jj = cp * 2 + e;
          int w2 = jj / 12, m12 = jj % 12;
          int lc = w2 * 48 + m12;
          int j = ns * 48 + jj;
          int l = j >> 7, ch = j & 127;
          float gf = scratch[row * kSstride + lc]      + bt[6 + (0 * 3 + l) * 128 + ch];
          float gi = scratch[row * kSstride + lc + 12] + bt[6 + (1 * 3 + l) * 128 + ch];
          float go = scratch[row * kSstride + lc + 24] + bt[6 + (2 * 3 + l) * 128 + ch];
          float gc = scratch[row * kSstride + lc + 36] + bt[6 + (3 * 3 + l) * 128 + ch];
          float fg = sigm(gf), ig = sigm(gi), og = sigm(go), ci = tanhf(gc);
          float fm = fmS[row * 4 + l], im = imS[row * 4 + l], ov = fm * im;
          float c0 = creg[it * 2 + e];
          float c1 = ov * (fg * c0 + ig * ci) + (fm - ov) * c0 + (im - ov) * ci;
          creg[it * 2 + e] = c1;
          hv[e] = og * tanhf(c1);
        }
        unsigned int packed =
            (unsigned int)bf16bits(hv[0]) | ((unsigned int)bf16bits(hv[1]) << 16);
        size_t eidx = ((size_t)(mt * 16 + row) * kH + ns * 48 + cp * 2) >> 1;
        __hip_atomic_store(&HoutU[eidx], packed, __ATOMIC_RELAXED,
                           __HIP_MEMORY_SCOPE_AGENT);
      }
    }

    // ---- publish: drain stores, then bump group counter ----
    asm volatile("s_waitcnt vmcnt(0)" ::: "memory");
    __syncthreads();
    if (tid == 0)
      __hip_atomic_fetch_add(cnt, 1, __ATOMIC_RELAXED, __HIP_MEMORY_SCOPE_AGENT);
  }
}

// ---------------------------------------------------------------------------
// Epilogue 1: per-b window softmax, Zbf = ld[k]*h (bf16), theme, hbase
// ---------------------------------------------------------------------------
__global__ void epi1_kernel(const int* __restrict__ vlen,
                            const float* __restrict__ Dhist,
                            const __hip_bfloat16* __restrict__ Hh,
                            __hip_bfloat16* __restrict__ Zbf, float* __restrict__ theme,
                            float* __restrict__ hbase) {
  int b = blockIdx.x, tid = threadIdx.x;
  int tb = vlen[b] - 1;
  float d[kK], ld[kK];
  float run = 0.f;
#pragma unroll
  for (int k = 0; k < kK; ++k) {
    int s = tb - (kK - 1) + k;
    float dv = (s >= 0) ? Dhist[(size_t)s * kB + b] : 0.f;
    run += dv;
    d[k] = run;
  }
  float m = d[0];
#pragma unroll
  for (int k = 1; k < kK; ++k) m = fmaxf(m, d[k]);
  float se = 0.f;
#pragma unroll
  for (int k = 0; k < kK; ++k) { ld[k] = __expf(d[k] - m); se += ld[k]; }
  float inv = 1.f / se;
#pragma unroll
  for (int k = 0; k < kK; ++k) ld[k] *= inv;

  for (int h = tid; h < kH; h += blockDim.x) {
    float th = 0.f;
#pragma unroll
    for (int k = 0; k < kK; ++k) {
      int s = tb - (kK - 1) + k;
      float hv = (s >= 0) ? __bfloat162float(Hh[((size_t)(s + 1) * kB + b) * kH + h]) : 0.f;
      float z = ld[k] * hv;
      Zbf[(size_t)b * (kK * kH) + k * kH + h] = __float2bfloat16(z);
      th += z;
    }
    theme[(size_t)b * kH + h] = th * (1.f / kK);
    hbase[(size_t)b * kH + h] = __bfloat162float(Hh[((size_t)(tb + 1) * kB + b) * kH + h]);
  }
}

// Epilogue 2: U = relu(theme @ scale_w + scale_b)   (512 x 64)
__global__ void epi2_kernel(const float* __restrict__ theme,
                            const float* __restrict__ scale_w,
                            const float* __restrict__ scale_b, float* __restrict__ U) {
  int b = blockIdx.x, o = threadIdx.x;
  __shared__ float tr[kH];
  for (int h = o; h < kH; h += 64) tr[h] = theme[(size_t)b * kH + h];
  __syncthreads();
  float a = scale_b[o];
  for (int h = 0; h < kH; ++h) a += tr[h] * scale_w[(size_t)h * 64 + o];
  U[(size_t)b * 64 + o] = fmaxf(a, 0.f);
}

// Epilogue 3: V = sigmoid(U @ rescale_w + rescale_b)   (512 x 384)
__global__ void epi3_kernel(const float* __restrict__ U,
                            const float* __restrict__ rescale_w,
                            const float* __restrict__ rescale_b, float* __restrict__ V) {
  int b = blockIdx.x, tid = threadIdx.x;
  __shared__ float ur[64];
  if (tid < 64) ur[tid] = U[(size_t)b * 64 + tid];
  __syncthreads();
  for (int o = tid; o < kH; o += 128) {
    float a = rescale_b[o];
#pragma unroll
    for (int k = 0; k < 64; ++k) a += ur[k] * rescale_w[(size_t)k * kH + o];
    V[(size_t)b * kH + o] = sigm(a);
  }
}

// Epilogue 4 (MFMA): ConvO = Zbf(512x3840) @ W2sw + conv_b. Grid (32 mt, 2 nh).
__global__ __launch_bounds__(256) void epi4m_kernel(const __hip_bfloat16* __restrict__ Zbf,
                                                    const __hip_bfloat16* __restrict__ W2sw,
                                                    const float* __restrict__ conv_b,
                                                    float* __restrict__ ConvO) {
  const int mt = blockIdx.x, nh = blockIdx.y;
  const int tid = threadIdx.x;
  const int lane = tid & 63, wave = tid >> 6;
  const int r16 = lane & 15, quad = lane >> 4;
  const int brow = mt * 16 + r16;
  const int n0w = nh * 192 + wave * 48;
  const __hip_bfloat16* Zrow = Zbf + (size_t)brow * (kK * kH);
  f32x4 acc[3];
#pragma unroll
  for (int t3 = 0; t3 < 3; ++t3) acc[t3] = (f32x4){0.f, 0.f, 0.f, 0.f};
  for (int c = 0; c < 120; ++c) {
    bf16x8 a = *(const bf16x8*)(Zrow + c * 32 + quad * 8);
#pragma unroll
    for (int t3 = 0; t3 < 3; ++t3) {
      bf16x8 bf = *(const bf16x8*)(W2sw + ((size_t)c * kH + n0w + t3 * 16 + r16) * 32 + quad * 8);
      acc[t3] = __builtin_amdgcn_mfma_f32_16x16x32_bf16(a, bf, acc[t3], 0, 0, 0);
    }
  }
#pragma unroll
  for (int t3 = 0; t3 < 3; ++t3) {
    int col = n0w + t3 * 16 + r16;
#pragma unroll
    for (int r = 0; r < 4; ++r)
      ConvO[(size_t)(mt * 16 + quad * 4 + r) * kH + col] = acc[t3][r] + conv_b[col];
  }
}

// Epilogue 5: out[b] = (V*ConvO + hbase) @ out_w + out_b
__global__ void epi5_kernel(const float* __restrict__ V, const float* __restrict__ ConvO,
                            const float* __restrict__ hbase,
                            const float* __restrict__ out_w,
                            const float* __restrict__ out_b, float* __restrict__ out) {
  int b = blockIdx.x, tid = threadIdx.x;
  __shared__ float r[kH];
  for (int h = tid; h < kH; h += 64)
    r[h] = V[(size_t)b * kH + h] * ConvO[(size_t)b * kH + h] + hbase[(size_t)b * kH + h];
  __syncthreads();
  if (tid < kLab) {
    float a = out_b[tid];
    for (int h = 0; h < kH; ++h) a += r[h] * out_w[(size_t)h * kLab + tid];
    out[(size_t)b * kLab + tid] = a;
  }
}

extern "C" void kernel_launch(void* const* d_in, const int* in_sizes, int n_in,
                              void* d_out, int out_size, void* d_ws, size_t ws_size,
                              hipStream_t stream) {
  (void)in_sizes; (void)n_in; (void)out_size; (void)ws_size;
  const float* X = (const float*)d_in[0];
  const int* vlen = (const int*)d_in[1];
  const float* kernel_w = (const float*)d_in[2];
  const float* kernel_b = (const float*)d_in[3];
  const float* rec_w = (const float*)d_in[4];
  const float* rec_b = (const float*)d_in[5];
  const float* scale_w = (const float*)d_in[6];
  const float* scale_b = (const float*)d_in[7];
  const float* rescale_w = (const float*)d_in[8];
  const float* rescale_b = (const float*)d_in[9];
  const float* conv_w = (const float*)d_in[10];
  const float* conv_b = (const float*)d_in[11];
  const float* out_w = (const float*)d_in[12];
  const float* out_b = (const float*)d_in[13];
  float* out = (float*)d_out;

  char* ws = (char*)d_ws;
  size_t off = 0;
  auto alloc = [&](size_t bytes) -> void* {
    void* p = ws + off;
    off += (bytes + 255) & ~(size_t)255;
    return p;
  };
  __hip_bfloat16* XW = (__hip_bfloat16*)alloc((size_t)kT * kB * kNsw * 2);      // 203.4 MB
  __hip_bfloat16* Hh = (__hip_bfloat16*)alloc((size_t)(kT + 1) * kB * kH * 2);  // 50.7 MB
  __hip_bfloat16* Wr_lin = (__hip_bfloat16*)alloc((size_t)1536 * 384 * 2);
  __hip_bfloat16* Wlog = (__hip_bfloat16*)alloc((size_t)12 * 16 * 32 * 2);
  __hip_bfloat16* Wx_sw = (__hip_bfloat16*)alloc((size_t)8 * kNsw * 32 * 2);
  __hip_bfloat16* W2sw = (__hip_bfloat16*)alloc((size_t)120 * kH * 32 * 2);
  float* bias = (float*)alloc((size_t)2 * kGates * 4);
  float* Dhist = (float*)alloc((size_t)kT * kB * 4);
  __hip_bfloat16* Zbf = (__hip_bfloat16*)alloc((size_t)kB * kK * kH * 2);
  float* theme = (float*)alloc((size_t)kB * kH * 4);
  float* hbase = (float*)alloc((size_t)kB * kH * 4);
  float* U = (float*)alloc((size_t)kB * 64 * 4);
  float* V = (float*)alloc((size_t)kB * kH * 4);
  float* ConvO = (float*)alloc((size_t)kB * kH * 4);
  int* Cnt = (int*)alloc((size_t)1024 * 4);

  hipLaunchKernelGGL(prep_kernel, dim3(1024), dim3(256), 0, stream, kernel_w, kernel_b,
                     rec_w, rec_b, conv_w, Wr_lin, Wlog, Wx_sw, W2sw, bias, Hh, Cnt);

  hipLaunchKernelGGL(xw_kernel, dim3(1024), dim3(256), 0, stream, X, Wx_sw, XW);

  constexpr unsigned kLds = 163840;  // exactly 160 KiB
  hipFuncSetAttribute((const void*)step_all, hipFuncAttributeMaxDynamicSharedMemorySize,
                      (int)kLds);
  {
    const __hip_bfloat16* a0 = Wr_lin;
    const __hip_bfloat16* a1 = Wlog;
    const float* a2 = bias;
    const __hip_bfloat16* a3 = XW;
    __hip_bfloat16* a4 = Hh;
    float* a5 = Dhist;
    int* a6 = Cnt;
    void* args[] = {&a0, &a1, &a2, &a3, &a4, &a5, &a6};
    hipLaunchCooperativeKernel((const void*)step_all, dim3(256), dim3(256), args, kLds,
                               stream);
  }

  hipLaunchKernelGGL(epi1_kernel, dim3(kB), dim3(128), 0, stream, vlen, Dhist, Hh, Zbf,
                     theme, hbase);
  hipLaunchKernelGGL(epi2_kernel, dim3(kB), dim3(64), 0, stream, theme, scale_w, scale_b, U);
  hipLaunchKernelGGL(epi3_kernel, dim3(kB), dim3(128), 0, stream, U, rescale_w, rescale_b, V);
  hipLaunchKernelGGL(epi4m_kernel, dim3(32, 2), dim3(256), 0, stream, Zbf, W2sw, conv_b,
                     ConvO);
  hipLaunchKernelGGL(epi5_kernel, dim3(kB), dim3(64), 0, stream, V, ConvO, hbase, out_w,
                     out_b, out);
}

// Round 8
// 1307.959 us; speedup vs baseline: 1.2492x; 1.2492x over previous
//
#include <hip/hip_runtime.h>
#include <hip/hip_bf16.h>

// Problem constants
constexpr int kB = 512, kT = 128, kF = 256, kH = 384, kK = 10, kLab = 25;
constexpr int kGates = 1542;        // 4H + 2L
constexpr int kNsw = 1552;          // 1536 swizzled gate cols + 6 logit + 10 pad (97 tiles)
constexpr int kWstride = 392;       // 384 K + 8 pad
constexpr int kSstride = 194;       // scratch [16 row][192 col + 2 pad]

typedef short bf16x8 __attribute__((ext_vector_type(8)));
typedef float f32x4 __attribute__((ext_vector_type(4)));

__device__ __forceinline__ float fast_sigm(float x) {
  return __builtin_amdgcn_rcpf(1.f + __expf(-x));
}
__device__ __forceinline__ float fast_tanh(float x) {
  x = fminf(fmaxf(x, -15.f), 15.f);
  float e = __expf(2.f * x);
  return (e - 1.f) * __builtin_amdgcn_rcpf(e + 1.f);
}
__device__ __forceinline__ unsigned short bf16bits(float x) {
  __hip_bfloat16 h = __float2bfloat16(x);
  return __builtin_bit_cast(unsigned short, h);
}

// swizzled col sc in [0,1536) -> original gate-space column
__device__ __forceinline__ int swcol_orig(int sc) {
  int ns = sc / 192, lc = sc % 192, w = lc / 48, wc = lc % 48;
  int g = wc / 12, jj = ns * 48 + w * 12 + wc % 12;
  int l = jj >> 7, ch = jj & 127;
  return 6 + (g * 3 + l) * 128 + ch;
}

// ---------------------------------------------------------------------------
// Prologue: build all swizzled bf16 weights + bias + zero h0 + zero sync cnt.
// ---------------------------------------------------------------------------
__global__ void prep_kernel(const float* __restrict__ kernel_w,
                            const float* __restrict__ kernel_b,
                            const float* __restrict__ rec_w,
                            const float* __restrict__ rec_b,
                            const float* __restrict__ conv_w,
                            __hip_bfloat16* __restrict__ Wr_lin,
                            __hip_bfloat16* __restrict__ Wlog,
                            __hip_bfloat16* __restrict__ Wx_sw,
                            __hip_bfloat16* __restrict__ W2sw,
                            float* __restrict__ bias,
                            __hip_bfloat16* __restrict__ Hh,
                            int* __restrict__ Cnt) {
  const long ntot = 1474560;  // W2sw size is the max job
  const long stride = (long)gridDim.x * blockDim.x;
  for (long i = (long)blockIdx.x * blockDim.x + threadIdx.x; i < ntot; i += stride) {
    // ---- W2sw: [c<120][n<384][32]
    {
      int j = (int)(i & 31);
      long r = i >> 5;
      int n = (int)(r % 384);
      int c = (int)(r / 384);
      int kk = c * 32 + j;
      int kc = kk / 384, h = kk % 384;
      W2sw[i] = __float2bfloat16(conv_w[((long)n * 384 + h) * 10 + kc]);
    }
    // ---- Wr_lin: 1536*384
    if (i < 589824) {
      int sc = (int)(i / 384), k = (int)(i % 384);
      Wr_lin[i] = __float2bfloat16(rec_w[(long)k * kGates + swcol_orig(sc)]);
    }
    // ---- Wx_sw: 8*1552*32 = 397312
    if (i < 397312) {
      int j = (int)(i & 31);
      long r = i >> 5;
      int n = (int)(r % kNsw);
      int c = (int)(r / kNsw);
      int k = c * 32 + j;
      int col = (n < 1536) ? swcol_orig(n) : ((n < 1542) ? (n - 1536) : -1);
      Wx_sw[i] = (col >= 0) ? __float2bfloat16(kernel_w[(long)k * kGates + col])
                            : __float2bfloat16(0.f);
    }
    // ---- Wlog: 12*16*32 = 6144
    if (i < 6144) {
      int j = (int)(i & 31);
      long r = i >> 5;
      int n = (int)(r % 16);
      int c = (int)(r / 16);
      int k = c * 32 + j;
      Wlog[i] = (n < 6) ? __float2bfloat16(rec_w[(long)k * kGates + n])
                        : __float2bfloat16(0.f);
    }
    // ---- bias
    if (i < kGates) {
      float b0 = kernel_b[i] + rec_b[i];
      bias[i] = b0;
      bias[kGates + i] = b0 + kernel_w[(long)kF * kGates + i] + rec_w[(long)kH * kGates + i];
    }
    // ---- zero h_{-1}
    if (i < (long)kB * kH) Hh[i] = __float2bfloat16(0.f);
    // ---- zero sync counters (ws is poisoned 0xAA before every launch)
    if (i < 1024) Cnt[i] = 0;
  }
}

// ---------------------------------------------------------------------------
// XW precompute: XW[t*512+b][1552] bf16 = X @ kernel_w (swizzled cols).
// ---------------------------------------------------------------------------
__global__ __launch_bounds__(256) void xw_kernel(const float* __restrict__ X,
                                                 const __hip_bfloat16* __restrict__ Wx_sw,
                                                 __hip_bfloat16* __restrict__ XW) {
  const int tid = threadIdx.x;
  const int lane = tid & 63, wave = tid >> 6;
  const int r16 = lane & 15, quad = lane >> 4;
  const int m0 = blockIdx.x * 64 + wave * 16;
  const int m = m0 + r16;
  const int t = m >> 9, b = m & 511;
  const float* xrow = X + ((size_t)b * kT + t) * kF;

  bf16x8 a[8];
#pragma unroll
  for (int c = 0; c < 8; ++c) {
    float4 p0 = *(const float4*)(xrow + c * 32 + quad * 8);
    float4 p1 = *(const float4*)(xrow + c * 32 + quad * 8 + 4);
    union { bf16x8 v; __hip_bfloat16 h[8]; } u;
    u.h[0] = __float2bfloat16(p0.x); u.h[1] = __float2bfloat16(p0.y);
    u.h[2] = __float2bfloat16(p0.z); u.h[3] = __float2bfloat16(p0.w);
    u.h[4] = __float2bfloat16(p1.x); u.h[5] = __float2bfloat16(p1.y);
    u.h[6] = __float2bfloat16(p1.z); u.h[7] = __float2bfloat16(p1.w);
    a[c] = u.v;
  }
  for (int tile = 0; tile < 97; ++tile) {
    f32x4 acc = (f32x4){0.f, 0.f, 0.f, 0.f};
#pragma unroll
    for (int c = 0; c < 8; ++c) {
      bf16x8 bf = *(const bf16x8*)(Wx_sw + ((size_t)c * kNsw + tile * 16 + r16) * 32 + quad * 8);
      acc = __builtin_amdgcn_mfma_f32_16x16x32_bf16(a[c], bf, acc, 0, 0, 0);
    }
#pragma unroll
    for (int r = 0; r < 4; ++r)
      XW[(size_t)(m0 + quad * 4 + r) * kNsw + tile * 16 + r16] = __float2bfloat16(acc[r]);
  }
}

// ---------------------------------------------------------------------------
// Persistent scan (R7 structure + coalesced exchange). 256 blocks, 256 thr.
// Changes vs R7 (each independently auditable):
//  1) publish mapping row=p/24,cp=p%24 -> consecutive tids write consecutive
//     u32 (was 768B-strided scatter; WRITE_SIZE showed 2x write-through blowup)
//  2) h consumed via ONE coalesced 12KB block load into XOR-swizzled LDS
//     (overlaid on scratch; disjoint lifetimes), ds_read_b128 frags.
//     Swizzle c16 ^= (row&7) at 16B granularity -> conflict-free both sides.
//  3) all-lane flag polling (no post-poll barrier); fast tanh/sigm.
// LDS: W 192x392 (150528) | hbuf 12288 / scratch 16x194 f32 (12416, union)
//      | Lg 16x6 (384) | fmS/imS (512)  == 163840 B.
// ---------------------------------------------------------------------------
__global__ __launch_bounds__(256, 1) void step_all(
    const __hip_bfloat16* __restrict__ Wr_lin, const __hip_bfloat16* __restrict__ Wlog,
    const float* __restrict__ bias, const __hip_bfloat16* __restrict__ XW,
    __hip_bfloat16* __restrict__ Hh, float* __restrict__ Dhist,
    int* __restrict__ Cnt) {
  extern __shared__ char smem[];
  __hip_bfloat16* Wl = (__hip_bfloat16*)smem;            // [192][392]
  char* hbufB = smem + 150528;                           // 12288B swizzled [16][768B]
  float* scratch = (float*)(smem + 150528);              // overlay (after frag reads)
  float* Lg = (float*)(smem + 162944);                   // [16][6]
  float* fmS = (float*)(smem + 163328);                  // [16][4]
  float* imS = (float*)(smem + 163584);                  // [16][4]

  const int bx = blockIdx.x;
  const int mt = bx >> 3, ns = bx & 7;
  const int tid = threadIdx.x;
  const int lane = tid & 63, wave = tid >> 6;
  const int r16 = lane & 15, quad = lane >> 4;
  int* cnt = Cnt + mt * 32;   // 128B-padded per-mt counter

  // one-time: stage W slice (contiguous 192*384 bf16) into padded LDS
  {
    const __hip_bfloat16* src = Wr_lin + (size_t)ns * 192 * 384;
    for (int i = tid; i < 192 * 384 / 8; i += 256) {
      int lc = (i * 8) / 384, k = (i * 8) % 384;
      *(bf16x8*)(Wl + lc * kWstride + k) = *(const bf16x8*)(src + i * 8);
    }
  }
  __syncthreads();

  float creg[2][2] = {{0.f, 0.f}, {0.f, 0.f}};

  for (int step = 0; step < kT; ++step) {
    const float* bt = bias + (step > 0 ? kGates : 0);

    // ---- XW prefetch (normal cached loads; independent of h) ----
    const __hip_bfloat16* XWrow = XW + (size_t)(step * kB + mt * 16) * kNsw;
    float xwv[3][4];
#pragma unroll
    for (int t3 = 0; t3 < 3; ++t3) {
      int col = ns * 192 + wave * 48 + t3 * 16 + r16;
#pragma unroll
      for (int r = 0; r < 4; ++r)
        xwv[t3][r] = __bfloat162float(XWrow[(size_t)(quad * 4 + r) * kNsw + col]);
    }
    float xlv[4] = {0.f, 0.f, 0.f, 0.f};
    if (wave == 0) {
#pragma unroll
      for (int r = 0; r < 4; ++r)
        xlv[r] = __bfloat162float(XWrow[(size_t)(quad * 4 + r) * kNsw + 1536 + r16]);
    }

    bf16x8 a[12];
    if (step > 0) {
      // ---- all-lane poll (same addr -> one transaction/wave; no barrier) ----
      const int target = 8 * step;
      while (__hip_atomic_load(cnt, __ATOMIC_RELAXED, __HIP_MEMORY_SCOPE_AGENT) < target) {
      }
      // ---- stage this mt's 12KB h slice into swizzled LDS (coalesced) ----
      const unsigned long long* src = (const unsigned long long*)
          ((const char*)Hh + (size_t)step * (kB * kH * 2) + (size_t)mt * 12288);
#pragma unroll
      for (int pass = 0; pass < 3; ++pass) {
        int L = pass * 256 + tid;          // 16B chunk index in [0,768)
        int row = L / 48, c16 = L % 48;
        union { unsigned long long q[2]; bf16x8 v; } u;
        u.q[0] = __hip_atomic_load(src + L * 2, __ATOMIC_RELAXED, __HIP_MEMORY_SCOPE_AGENT);
        u.q[1] = __hip_atomic_load(src + L * 2 + 1, __ATOMIC_RELAXED, __HIP_MEMORY_SCOPE_AGENT);
        int sw = (c16 & ~7) | ((c16 & 7) ^ (row & 7));
        *(bf16x8*)(hbufB + row * 768 + sw * 16) = u.v;
      }
      __syncthreads();
      // ---- frag reads from swizzled hbuf ----
#pragma unroll
      for (int c = 0; c < 12; ++c) {
        int c16 = c * 4 + quad;
        int sw = (c16 & ~7) | ((c16 & 7) ^ (r16 & 7));
        a[c] = *(const bf16x8*)(hbufB + r16 * 768 + sw * 16);
      }
      __syncthreads();   // all frag reads done -> hbuf reusable as scratch
    }

    f32x4 acc[3];
#pragma unroll
    for (int t3 = 0; t3 < 3; ++t3) {
#pragma unroll
      for (int r = 0; r < 4; ++r) acc[t3][r] = xwv[t3][r];
    }
    f32x4 accL = (f32x4){xlv[0], xlv[1], xlv[2], xlv[3]};

    if (step > 0) {
#pragma unroll
      for (int c = 0; c < 12; ++c) {
#pragma unroll
        for (int t3 = 0; t3 < 3; ++t3) {
          bf16x8 bf = *(const bf16x8*)(Wl + (wave * 48 + t3 * 16 + r16) * kWstride + c * 32 + quad * 8);
          acc[t3] = __builtin_amdgcn_mfma_f32_16x16x32_bf16(a[c], bf, acc[t3], 0, 0, 0);
        }
        if (wave == 0) {
          bf16x8 bfl = *(const bf16x8*)(Wlog + ((size_t)c * 16 + r16) * 32 + quad * 8);
          accL = __builtin_amdgcn_mfma_f32_16x16x32_bf16(a[c], bfl, accL, 0, 0, 0);
        }
      }
    }

    if (wave == 0 && r16 < 6) {
#pragma unroll
      for (int r = 0; r < 4; ++r) Lg[(quad * 4 + r) * 6 + r16] = accL[r] + bt[r16];
    }
#pragma unroll
    for (int t3 = 0; t3 < 3; ++t3) {
      int colb = wave * 48 + t3 * 16 + r16;
#pragma unroll
      for (int r = 0; r < 4; ++r) scratch[(quad * 4 + r) * kSstride + colb] = acc[t3][r];
    }
    __syncthreads();

    if (tid < 16) {
      float z0 = Lg[tid * 6 + 0], z1 = Lg[tid * 6 + 1], z2 = Lg[tid * 6 + 2];
      float m = fmaxf(z0, fmaxf(z1, z2));
      float e0 = __expf(z0 - m), e1 = __expf(z1 - m), e2 = __expf(z2 - m);
      float inv = 1.f / (e0 + e1 + e2);
      float fm0 = e0 * inv, fm1 = (e0 + e1) * inv, fm2 = 1.f;
      float z3 = Lg[tid * 6 + 3], z4 = Lg[tid * 6 + 4], z5 = Lg[tid * 6 + 5];
      float m2 = fmaxf(z3, fmaxf(z4, z5));
      float e3 = __expf(z3 - m2), e4 = __expf(z4 - m2), e5 = __expf(z5 - m2);
      float inv2 = 1.f / (e3 + e4 + e5);
      fmS[tid * 4 + 0] = fm0; fmS[tid * 4 + 1] = fm1; fmS[tid * 4 + 2] = fm2;
      imS[tid * 4 + 0] = 1.f;
      imS[tid * 4 + 1] = (e4 + e5) * inv2;
      imS[tid * 4 + 2] = e5 * inv2;
      if (ns == 0)
        Dhist[(size_t)step * kB + mt * 16 + tid] = 1.f - (fm0 + fm1 + fm2) * (1.f / 3.f);
    }
    __syncthreads();

    // ---- cell update + COALESCED packed agent-scope publish ----
    unsigned int* HoutU = (unsigned int*)(Hh + (size_t)(step + 1) * kB * kH);
#pragma unroll
    for (int it = 0; it < 2; ++it) {
      int p = tid + it * 256;
      if (p < 384) {
        int row = p / 24, cp = p % 24;   // consecutive tid -> consecutive u32
        float hv[2];
#pragma unroll
        for (int e = 0; e < 2; ++e) {
          int jj = cp * 2 + e;
          int w2 = jj / 12, m12 = jj % 12;
          int lc = w2 * 48 + m12;
          int j = ns * 48 + jj;
          int l = j >> 7, ch = j & 127;
          float gf = scratch[row * kSstride + lc]      + bt[6 + (0 * 3 + l) * 128 + ch];
          float gi = scratch[row * kSstride + lc + 12] + bt[6 + (1 * 3 + l) * 128 + ch];
          float go = scratch[row * kSstride + lc + 24] + bt[6 + (2 * 3 + l) * 128 + ch];
          float gc = scratch[row * kSstride + lc + 36] + bt[6 + (3 * 3 + l) * 128 + ch];
          float fg = fast_sigm(gf), ig = fast_sigm(gi);
          float og = fast_sigm(go), ci = fast_tanh(gc);
          float fm = fmS[row * 4 + l], im = imS[row * 4 + l], ov = fm * im;
          float c0 = creg[it][e];
          float c1 = ov * (fg * c0 + ig * ci) + (fm - ov) * c0 + (im - ov) * ci;
          creg[it][e] = c1;
          hv[e] = og * fast_tanh(c1);
        }
        unsigned int packed =
            (unsigned int)bf16bits(hv[0]) | ((unsigned int)bf16bits(hv[1]) << 16);
        __hip_atomic_store(&HoutU[(size_t)(mt * 16 + row) * 192 + ns * 24 + cp], packed,
                           __ATOMIC_RELAXED, __HIP_MEMORY_SCOPE_AGENT);
      }
    }

    // ---- publish: drain stores, then bump group counter ----
    asm volatile("s_waitcnt vmcnt(0)" ::: "memory");
    __syncthreads();
    if (tid == 0)
      __hip_atomic_fetch_add(cnt, 1, __ATOMIC_RELAXED, __HIP_MEMORY_SCOPE_AGENT);
  }
}

// ---------------------------------------------------------------------------
// Epilogue 1: per-b window softmax, Zbf = ld[k]*h (bf16), theme, hbase
// ---------------------------------------------------------------------------
__global__ void epi1_kernel(const int* __restrict__ vlen,
                            const float* __restrict__ Dhist,
                            const __hip_bfloat16* __restrict__ Hh,
                            __hip_bfloat16* __restrict__ Zbf, float* __restrict__ theme,
                            float* __restrict__ hbase) {
  int b = blockIdx.x, tid = threadIdx.x;
  int tb = vlen[b] - 1;
  float d[kK], ld[kK];
  float run = 0.f;
#pragma unroll
  for (int k = 0; k < kK; ++k) {
    int s = tb - (kK - 1) + k;
    float dv = (s >= 0) ? Dhist[(size_t)s * kB + b] : 0.f;
    run += dv;
    d[k] = run;
  }
  float m = d[0];
#pragma unroll
  for (int k = 1; k < kK; ++k) m = fmaxf(m, d[k]);
  float se = 0.f;
#pragma unroll
  for (int k = 0; k < kK; ++k) { ld[k] = __expf(d[k] - m); se += ld[k]; }
  float inv = 1.f / se;
#pragma unroll
  for (int k = 0; k < kK; ++k) ld[k] *= inv;

  for (int h = tid; h < kH; h += blockDim.x) {
    float th = 0.f;
#pragma unroll
    for (int k = 0; k < kK; ++k) {
      int s = tb - (kK - 1) + k;
      float hv = (s >= 0) ? __bfloat162float(Hh[((size_t)(s + 1) * kB + b) * kH + h]) : 0.f;
      float z = ld[k] * hv;
      Zbf[(size_t)b * (kK * kH) + k * kH + h] = __float2bfloat16(z);
      th += z;
    }
    theme[(size_t)b * kH + h] = th * (1.f / kK);
    hbase[(size_t)b * kH + h] = __bfloat162float(Hh[((size_t)(tb + 1) * kB + b) * kH + h]);
  }
}

// Epilogue 2: U = relu(theme @ scale_w + scale_b)   (512 x 64)
__global__ void epi2_kernel(const float* __restrict__ theme,
                            const float* __restrict__ scale_w,
                            const float* __restrict__ scale_b, float* __restrict__ U) {
  int b = blockIdx.x, o = threadIdx.x;
  __shared__ float tr[kH];
  for (int h = o; h < kH; h += 64) tr[h] = theme[(size_t)b * kH + h];
  __syncthreads();
  float a = scale_b[o];
  for (int h = 0; h < kH; ++h) a += tr[h] * scale_w[(size_t)h * 64 + o];
  U[(size_t)b * 64 + o] = fmaxf(a, 0.f);
}

// Epilogue 3: V = sigmoid(U @ rescale_w + rescale_b)   (512 x 384)
__global__ void epi3_kernel(const float* __restrict__ U,
                            const float* __restrict__ rescale_w,
                            const float* __restrict__ rescale_b, float* __restrict__ V) {
  int b = blockIdx.x, tid = threadIdx.x;
  __shared__ float ur[64];
  if (tid < 64) ur[tid] = U[(size_t)b * 64 + tid];
  __syncthreads();
  for (int o = tid; o < kH; o += 128) {
    float a = rescale_b[o];
#pragma unroll
    for (int k = 0; k < 64; ++k) a += ur[k] * rescale_w[(size_t)k * kH + o];
    V[(size_t)b * kH + o] = 1.f / (1.f + __expf(-a));
  }
}

// Epilogue 4 (MFMA): ConvO = Zbf(512x3840) @ W2sw + conv_b. Grid (32 mt, 2 nh).
__global__ __launch_bounds__(256) void epi4m_kernel(const __hip_bfloat16* __restrict__ Zbf,
                                                    const __hip_bfloat16* __restrict__ W2sw,
                                                    const float* __restrict__ conv_b,
                                                    float* __restrict__ ConvO) {
  const int mt = blockIdx.x, nh = blockIdx.y;
  const int tid = threadIdx.x;
  const int lane = tid & 63, wave = tid >> 6;
  const int r16 = lane & 15, quad = lane >> 4;
  const int brow = mt * 16 + r16;
  const int n0w = nh * 192 + wave * 48;
  const __hip_bfloat16* Zrow = Zbf + (size_t)brow * (kK * kH);
  f32x4 acc[3];
#pragma unroll
  for (int t3 = 0; t3 < 3; ++t3) acc[t3] = (f32x4){0.f, 0.f, 0.f, 0.f};
  for (int c = 0; c < 120; ++c) {
    bf16x8 a = *(const bf16x8*)(Zrow + c * 32 + quad * 8);
#pragma unroll
    for (int t3 = 0; t3 < 3; ++t3) {
      bf16x8 bf = *(const bf16x8*)(W2sw + ((size_t)c * kH + n0w + t3 * 16 + r16) * 32 + quad * 8);
      acc[t3] = __builtin_amdgcn_mfma_f32_16x16x32_bf16(a, bf, acc[t3], 0, 0, 0);
    }
  }
#pragma unroll
  for (int t3 = 0; t3 < 3; ++t3) {
    int col = n0w + t3 * 16 + r16;
#pragma unroll
    for (int r = 0; r < 4; ++r)
      ConvO[(size_t)(mt * 16 + quad * 4 + r) * kH + col] = acc[t3][r] + conv_b[col];
  }
}

// Epilogue 5: out[b] = (V*ConvO + hbase) @ out_w + out_b
__global__ void epi5_kernel(const float* __restrict__ V, const float* __restrict__ ConvO,
                            const float* __restrict__ hbase,
                            const float* __restrict__ out_w,
                            const float* __restrict__ out_b, float* __restrict__ out) {
  int b = blockIdx.x, tid = threadIdx.x;
  __shared__ float r[kH];
  for (int h = tid; h < kH; h += 64)
    r[h] = V[(size_t)b * kH + h] * ConvO[(size_t)b * kH + h] + hbase[(size_t)b * kH + h];
  __syncthreads();
  if (tid < kLab) {
    float a = out_b[tid];
    for (int h = 0; h < kH; ++h) a += r[h] * out_w[(size_t)h * kLab + tid];
    out[(size_t)b * kLab + tid] = a;
  }
}

extern "C" void kernel_launch(void* const* d_in, const int* in_sizes, int n_in,
                              void* d_out, int out_size, void* d_ws, size_t ws_size,
                              hipStream_t stream) {
  (void)in_sizes; (void)n_in; (void)out_size; (void)ws_size;
  const float* X = (const float*)d_in[0];
  const int* vlen = (const int*)d_in[1];
  const float* kernel_w = (const float*)d_in[2];
  const float* kernel_b = (const float*)d_in[3];
  const float* rec_w = (const float*)d_in[4];
  const float* rec_b = (const float*)d_in[5];
  const float* scale_w = (const float*)d_in[6];
  const float* scale_b = (const float*)d_in[7];
  const float* rescale_w = (const float*)d_in[8];
  const float* rescale_b = (const float*)d_in[9];
  const float* conv_w = (const float*)d_in[10];
  const float* conv_b = (const float*)d_in[11];
  const float* out_w = (const float*)d_in[12];
  const float* out_b = (const float*)d_in[13];
  float* out = (float*)d_out;

  char* ws = (char*)d_ws;
  size_t off = 0;
  auto alloc = [&](size_t bytes) -> void* {
    void* p = ws + off;
    off += (bytes + 255) & ~(size_t)255;
    return p;
  };
  __hip_bfloat16* XW = (__hip_bfloat16*)alloc((size_t)kT * kB * kNsw * 2);      // 203.4 MB
  __hip_bfloat16* Hh = (__hip_bfloat16*)alloc((size_t)(kT + 1) * kB * kH * 2);  // 50.7 MB
  __hip_bfloat16* Wr_lin = (__hip_bfloat16*)alloc((size_t)1536 * 384 * 2);
  __hip_bfloat16* Wlog = (__hip_bfloat16*)alloc((size_t)12 * 16 * 32 * 2);
  __hip_bfloat16* Wx_sw = (__hip_bfloat16*)alloc((size_t)8 * kNsw * 32 * 2);
  __hip_bfloat16* W2sw = (__hip_bfloat16*)alloc((size_t)120 * kH * 32 * 2);
  float* bias = (float*)alloc((size_t)2 * kGates * 4);
  float* Dhist = (float*)alloc((size_t)kT * kB * 4);
  __hip_bfloat16* Zbf = (__hip_bfloat16*)alloc((size_t)kB * kK * kH * 2);
  float* theme = (float*)alloc((size_t)kB * kH * 4);
  float* hbase = (float*)alloc((size_t)kB * kH * 4);
  float* U = (float*)alloc((size_t)kB * 64 * 4);
  float* V = (float*)alloc((size_t)kB * kH * 4);
  float* ConvO = (float*)alloc((size_t)kB * kH * 4);
  int* Cnt = (int*)alloc((size_t)1024 * 4);

  hipLaunchKernelGGL(prep_kernel, dim3(1024), dim3(256), 0, stream, kernel_w, kernel_b,
                     rec_w, rec_b, conv_w, Wr_lin, Wlog, Wx_sw, W2sw, bias, Hh, Cnt);

  hipLaunchKernelGGL(xw_kernel, dim3(1024), dim3(256), 0, stream, X, Wx_sw, XW);

  constexpr unsigned kLds = 163840;  // exactly 160 KiB
  hipFuncSetAttribute((const void*)step_all, hipFuncAttributeMaxDynamicSharedMemorySize,
                      (int)kLds);
  {
    const __hip_bfloat16* a0 = Wr_lin;
    const __hip_bfloat16* a1 = Wlog;
    const float* a2 = bias;
    const __hip_bfloat16* a3 = XW;
    __hip_bfloat16* a4 = Hh;
    float* a5 = Dhist;
    int* a6 = Cnt;
    void* args[] = {&a0, &a1, &a2, &a3, &a4, &a5, &a6};
    hipLaunchCooperativeKernel((const void*)step_all, dim3(256), dim3(256), args, kLds,
                               stream);
  }

  hipLaunchKernelGGL(epi1_kernel, dim3(kB), dim3(128), 0, stream, vlen, Dhist, Hh, Zbf,
                     theme, hbase);
  hipLaunchKernelGGL(epi2_kernel, dim3(kB), dim3(64), 0, stream, theme, scale_w, scale_b, U);
  hipLaunchKernelGGL(epi3_kernel, dim3(kB), dim3(128), 0, stream, U, rescale_w, rescale_b, V);
  hipLaunchKernelGGL(epi4m_kernel, dim3(32, 2), dim3(256), 0, stream, Zbf, W2sw, conv_b,
                     ConvO);
  hipLaunchKernelGGL(epi5_kernel, dim3(kB), dim3(64), 0, stream, V, ConvO, hbase, out_w,
                     out_b, out);
}